// Round 4
// baseline (311.594 us; speedup 1.0000x reference)
//
#include <hip/hip_runtime.h>

// GraphAttentionLayer: B=8, N=2048, E=128, H=4, D=32.
// Runtime input-dtype dispatch: k_detect sniffs whether float tensors are
// fp32 or bf16 (device flag; wave-uniform branch; capture-safe).
// Pipeline: k_detect ; k_mask (adj[0]->bitmask) ; k_qkv (MFMA GEMM ->
// Q*scale, K, V^T, bf16 internal) ; k_attn (flash, S^T=K@Q^T, permuted key
// rows so P^T == mfma32 B-frag) ; k_proj (writes d_out in detected dtype).
// Only the m89-verified __builtin_amdgcn_mfma_f32_16x16x32_bf16 is used.
// ws: Qg@0 Kg@4M Vt@8M mb@12M flag@12.5M Oa@13M (Oa used in fp32 mode only).

#define EDIM 128
#define SCALE 0.17677669529663687f

typedef unsigned int uint32;
typedef float f32x4 __attribute__((ext_vector_type(4)));
typedef short s16x8 __attribute__((ext_vector_type(8)));

__device__ inline float bf2f(ushort u) { return __uint_as_float(((uint32)u) << 16); }
__device__ inline ushort f2bf(float f) {            // round-to-nearest-even
  uint32 u = __float_as_uint(f);
  u += 0x7fffu + ((u >> 16) & 1u);
  return (ushort)(u >> 16);
}

__device__ inline f32x4 mfma32(s16x8 a, s16x8 b, f32x4 c) {
  return __builtin_amdgcn_mfma_f32_16x16x32_bf16(a, b, c, 0, 0, 0);
}

// Load 8 consecutive elements (element index e, e%8==0) as bf16 frag,
// from either an fp32 or a bf16 array.
__device__ inline s16x8 load8(const void* p, size_t e, int fp32) {
  if (fp32) {
    const float* f = (const float*)p + e;
    float4 lo = *(const float4*)f;
    float4 hi = *(const float4*)(f + 4);
    s16x8 r;
    r[0] = (short)f2bf(lo.x); r[1] = (short)f2bf(lo.y);
    r[2] = (short)f2bf(lo.z); r[3] = (short)f2bf(lo.w);
    r[4] = (short)f2bf(hi.x); r[5] = (short)f2bf(hi.y);
    r[6] = (short)f2bf(hi.z); r[7] = (short)f2bf(hi.w);
    return r;
  }
  return *(const s16x8*)((const ushort*)p + e);
}
__device__ inline float loads(const void* p, size_t e, int fp32) {
  return fp32 ? ((const float*)p)[e] : bf2f(((const ushort*)p)[e]);
}

// ---------------- dtype sniffer: even halfwords of x. bf16 data -> bf16
// exponent in [100,140] ~100% of the time; fp32 data -> those halfwords are
// mantissa bits, in-range only ~16%. flag=1 means fp32.
__global__ void k_detect(const ushort* __restrict__ xus, int* __restrict__ flag) {
  int lane = threadIdx.x;                    // 64 threads
  int cnt = 0;
#pragma unroll
  for (int i = 0; i < 4; i++) {
    ushort v = xus[2 * (lane * 4 + i)];
    int ex = (v >> 7) & 0xFF;
    cnt += (ex >= 100 && ex <= 140) ? 1 : 0;
  }
#pragma unroll
  for (int s = 1; s < 64; s <<= 1) cnt += __shfl_xor(cnt, s);
  if (lane == 0) *flag = (cnt < 128) ? 1 : 0;
}

// ---------------- mask: adj[0] (2048x2048 int32) -> bitmask (bit=1 keep)
__global__ __launch_bounds__(256) void k_mask(const int* __restrict__ adj,
                                              uint32* __restrict__ mb) {
  int idx = blockIdx.x * 256 + threadIdx.x;
  int a = adj[idx];
  unsigned long long bal = __ballot(a != 0);
  int lane = threadIdx.x & 63;
  if (lane == 0)  mb[idx >> 5] = (uint32)bal;
  if (lane == 32) mb[idx >> 5] = (uint32)(bal >> 32);
}

// ---------------- QKV projection: x(16384x128) @ W^T(128x384) + b
__global__ __launch_bounds__(256) void k_qkv(const void* __restrict__ x,
                                             const void* __restrict__ w,
                                             const void* __restrict__ bias,
                                             ushort* __restrict__ Qg,
                                             ushort* __restrict__ Kg,
                                             ushort* __restrict__ Vtg,
                                             const int* __restrict__ flagp) {
  const int fp32 = *flagp;
  const int tid = threadIdx.x;
  const int wave = tid >> 6, lane = tid & 63, L = lane & 15, quad = lane >> 4;
  const int mt = blockIdx.x * 64 + wave * 16;
  const int jt0 = blockIdx.y * 8;

  s16x8 a[4];
#pragma unroll
  for (int ks = 0; ks < 4; ks++)
    a[ks] = load8(x, (size_t)(mt + L) * EDIM + ks * 32 + quad * 8, fp32);

  const int bidx = mt >> 11;                 // batch
  const int npos0 = (mt & 2047) + quad * 4;  // n position of reg 0

  for (int jj = 0; jj < 8; jj++) {
    int jt = jt0 + jj;
    f32x4 acc = {0.f, 0.f, 0.f, 0.f};
#pragma unroll
    for (int ks = 0; ks < 4; ks++) {
      s16x8 bf = load8(w, (size_t)(jt * 16 + L) * EDIM + ks * 32 + quad * 8, fp32);
      acc = mfma32(a[ks], bf, acc);          // A = x rows, B = W rows
    }
    int j = jt * 16 + L;
    float badd = loads(bias, j, fp32);
    int jm = j & 127;
    int h = jm >> 5, d = jm & 31;
    int bh = bidx * 4 + h;
    if (jt < 8) {              // Q, pre-scaled by 1/sqrt(D)
#pragma unroll
      for (int r = 0; r < 4; r++)
        Qg[(size_t)bh * 65536 + (size_t)(npos0 + r) * 32 + d] = f2bf((acc[r] + badd) * SCALE);
    } else if (jt < 16) {      // K
#pragma unroll
      for (int r = 0; r < 4; r++)
        Kg[(size_t)bh * 65536 + (size_t)(npos0 + r) * 32 + d] = f2bf(acc[r] + badd);
    } else {                   // V transposed: Vt[bh][d][n]
      ushort4 pk;
      pk.x = f2bf(acc[0] + badd); pk.y = f2bf(acc[1] + badd);
      pk.z = f2bf(acc[2] + badd); pk.w = f2bf(acc[3] + badd);
      *(ushort4*)(Vtg + (size_t)bh * 65536 + (size_t)d * 2048 + npos0) = pk;
    }
  }
}

// ---------------- flash attention. Block = 4 waves x 16 queries, one (b,h).
// S^T = K@Q^T with permuted key rows: tile0 row i <- key (i>>2)*8+(i&3),
// tile1 +4; lane (quad,L) then holds P^T keys quad*8+{0..7} = mfma32 B-frag.
// Destination: d_out (bf16 mode) or Oa in ws (fp32 mode), bf16 either way.
__global__ __launch_bounds__(256) void k_attn(const ushort* __restrict__ Qg,
                                              const ushort* __restrict__ Kg,
                                              const ushort* __restrict__ Vtg,
                                              const uint32* __restrict__ mb,
                                              ushort* Oglob, ushort* Oa,
                                              const int* __restrict__ flagp) {
  __shared__ ushort Klds[128 * 32];    // [key][dim]
  __shared__ ushort Vtlds[32 * 128];   // [dim][key], granule-swizzled by d&7

  const int fp32 = *flagp;
  ushort* O = fp32 ? Oa : Oglob;

  const int tid = threadIdx.x;
  const int wave = tid >> 6, lane = tid & 63, L = lane & 15, quad = lane >> 4;
  const int bh = blockIdx.x >> 5;
  const int qblk = blockIdx.x & 31;
  const int qg = qblk * 64 + wave * 16 + L;          // this lane's query row

  const ushort* Qrow = Qg + (size_t)bh * 65536 + (size_t)qg * 32;
  s16x8 qfrag = *(const s16x8*)(Qrow + quad * 8);    // B-frag: all 32 dims

  f32x4 Ot0 = {0, 0, 0, 0}, Ot1 = {0, 0, 0, 0};     // O^T, d 0..15 / 16..31
  float mrun = -1.0e30f, lrun = 0.f;

  const ushort* Kbase = Kg + (size_t)bh * 65536;
  const ushort* Vbase = Vtg + (size_t)bh * 65536;
  const int krow0 = ((L >> 2) * 8) + (L & 3);        // permuted key row, tile0

  for (int c = 0; c < 16; c++) {                     // 128-key chunks
    __syncthreads();
#pragma unroll
    for (int r = 0; r < 2; r++) {                    // cooperative staging
      int idx = r * 256 + tid;
      int row = idx >> 2, seg = idx & 3;             // K: 128 rows x 4 segs
      s16x8 kv = *(const s16x8*)(Kbase + (size_t)(c * 128 + row) * 32 + seg * 8);
      *(s16x8*)&Klds[row * 32 + seg * 8] = kv;
      int dd = idx >> 4, vseg = idx & 15;            // Vt: 32 rows x 16 granules
      s16x8 vv = *(const s16x8*)(Vbase + (size_t)dd * 2048 + c * 128 + vseg * 8);
      *(s16x8*)&Vtlds[dd * 128 + (vseg ^ (dd & 7)) * 8] = vv;
    }
    __syncthreads();

    uint4 mws = *(const uint4*)(mb + (size_t)qg * 64 + c * 4);
    uint32 mwarr[4] = {mws.x, mws.y, mws.z, mws.w};

#pragma unroll
    for (int sub = 0; sub < 4; sub++) {              // 32-key subchunks
      uint32 mwq = mwarr[sub] >> (quad * 8);         // keys quad*8..quad*8+7
      const f32x4 Z = {0, 0, 0, 0};
      int r0 = sub * 32 + krow0;
      s16x8 kf0 = *(const s16x8*)&Klds[r0 * 32 + quad * 8];
      s16x8 kf1 = *(const s16x8*)&Klds[(r0 + 4) * 32 + quad * 8];
      f32x4 st0 = mfma32(kf0, qfrag, Z);             // keys quad*8+r
      f32x4 st1 = mfma32(kf1, qfrag, Z);             // keys quad*8+4+r

      float s0[4], s1[4];
#pragma unroll
      for (int r = 0; r < 4; r++) {
        s0[r] = st0[r] + (((mwq >> r) & 1u) ? 0.f : -1e9f);
        s1[r] = st1[r] + (((mwq >> (4 + r)) & 1u) ? 0.f : -1e9f);
      }
      float cm = fmaxf(fmaxf(fmaxf(s0[0], s0[1]), fmaxf(s0[2], s0[3])),
                       fmaxf(fmaxf(s1[0], s1[1]), fmaxf(s1[2], s1[3])));
      cm = fmaxf(cm, __shfl_xor(cm, 16));
      cm = fmaxf(cm, __shfl_xor(cm, 32));
      float mn = fmaxf(mrun, cm);
      float corr = __expf(mrun - mn);
      float p0[4], p1[4], ps = 0.f;
#pragma unroll
      for (int r = 0; r < 4; r++) {
        p0[r] = __expf(s0[r] - mn);
        p1[r] = __expf(s1[r] - mn);
        ps += p0[r] + p1[r];
      }
      ps += __shfl_xor(ps, 16);
      ps += __shfl_xor(ps, 32);
      lrun = lrun * corr + ps;
      mrun = mn;
#pragma unroll
      for (int r = 0; r < 4; r++) { Ot0[r] *= corr; Ot1[r] *= corr; }

      s16x8 pf;                                      // P^T as mfma32 B-frag
#pragma unroll
      for (int r = 0; r < 4; r++) {
        pf[r]     = (short)f2bf(p0[r]);
        pf[4 + r] = (short)f2bf(p1[r]);
      }
#pragma unroll
      for (int dt = 0; dt < 2; dt++) {               // O^T += V^T @ P^T
        int d0 = dt * 16 + L;
        int g = (sub * 4 + quad) ^ (d0 & 7);         // swizzled granule
        s16x8 vf = *(const s16x8*)&Vtlds[d0 * 128 + g * 8];
        if (dt == 0) Ot0 = mfma32(vf, pf, Ot0);
        else         Ot1 = mfma32(vf, pf, Ot1);
      }
    }
  }

  float rn = 1.0f / lrun;
  int b = bh >> 2, h = bh & 3;
  size_t obase = ((size_t)(b * 2048 + qg)) * 128 + h * 32 + quad * 4;
  ushort4 pk0, pk1;
  pk0.x = f2bf(Ot0[0] * rn); pk0.y = f2bf(Ot0[1] * rn);
  pk0.z = f2bf(Ot0[2] * rn); pk0.w = f2bf(Ot0[3] * rn);
  pk1.x = f2bf(Ot1[0] * rn); pk1.y = f2bf(Ot1[1] * rn);
  pk1.z = f2bf(Ot1[2] * rn); pk1.w = f2bf(Ot1[3] * rn);
  *(ushort4*)(O + obase) = pk0;
  *(ushort4*)(O + obase + 16) = pk1;
}

// ---------------- output projection: act(16384x128) @ out_w^T + out_b.
// bf16 mode: in-place on d_out (wave loads its own 16 rows first — safe).
// fp32 mode: reads Oa from ws, writes float32 to d_out. No __restrict__:
// src may alias outp.
__global__ __launch_bounds__(256) void k_proj(void* outp, const ushort* Oa,
                                              const void* w, const void* bias,
                                              const int* flagp) {
  const int fp32 = *flagp;
  const ushort* src = fp32 ? Oa : (const ushort*)outp;
  const int tid = threadIdx.x;
  const int wave = tid >> 6, lane = tid & 63, L = lane & 15, quad = lane >> 4;
  const int mt = blockIdx.x * 64 + wave * 16;

  s16x8 a[4];
#pragma unroll
  for (int ks = 0; ks < 4; ks++)
    a[ks] = *(const s16x8*)(src + (size_t)(mt + L) * EDIM + ks * 32 + quad * 8);

  for (int jt = 0; jt < 8; jt++) {
    f32x4 acc = {0.f, 0.f, 0.f, 0.f};
#pragma unroll
    for (int ks = 0; ks < 4; ks++) {
      s16x8 bf = load8(w, (size_t)(jt * 16 + L) * EDIM + ks * 32 + quad * 8, fp32);
      acc = mfma32(a[ks], bf, acc);
    }
    float badd = loads(bias, jt * 16 + L, fp32);
#pragma unroll
    for (int r = 0; r < 4; r++) {
      size_t idx = (size_t)(mt + quad * 4 + r) * EDIM + jt * 16 + L;
      if (fp32) ((float*)outp)[idx] = acc[r] + badd;
      else      ((ushort*)outp)[idx] = f2bf(acc[r] + badd);
    }
  }
}

extern "C" void kernel_launch(void* const* d_in, const int* in_sizes, int n_in,
                              void* d_out, int out_size, void* d_ws, size_t ws_size,
                              hipStream_t stream) {
  const void* x   = d_in[0];
  const int*  adj = (const int*)d_in[1];
  const void* ipw = d_in[2];
  const void* ipb = d_in[3];
  const void* ow  = d_in[4];
  const void* ob  = d_in[5];

  char* ws = (char*)d_ws;
  ushort* Qg  = (ushort*)(ws);
  ushort* Kg  = (ushort*)(ws + ((size_t)4 << 20));
  ushort* Vtg = (ushort*)(ws + ((size_t)8 << 20));
  uint32* mb  = (uint32*)(ws + ((size_t)12 << 20));
  int*    fl  = (int*)(ws + ((size_t)12 << 20) + (512 << 10));
  ushort* Oa  = (ushort*)(ws + ((size_t)13 << 20));   // fp32 mode only

  hipLaunchKernelGGL(k_detect, dim3(1), dim3(64), 0, stream, (const ushort*)x, fl);
  hipLaunchKernelGGL(k_mask, dim3(16384), dim3(256), 0, stream, adj, mb);
  hipLaunchKernelGGL(k_qkv, dim3(256, 3), dim3(256), 0, stream, x, ipw, ipb, Qg, Kg, Vtg, fl);
  hipLaunchKernelGGL(k_attn, dim3(1024), dim3(256), 0, stream, Qg, Kg, Vtg, mb,
                     (ushort*)d_out, Oa, fl);
  hipLaunchKernelGGL(k_proj, dim3(256), dim3(256), 0, stream, d_out, Oa, ow, ob, fl);
}

// Round 6
// 289.285 us; speedup vs baseline: 1.0771x; 1.0771x over previous
//
#include <hip/hip_runtime.h>

// GraphAttentionLayer: B=8, N=2048, E=128, H=4, D=32. fp32 in/out (detected).
// k_mask (adj[0]->bitmask + dtype detect) ; k_qkv (MFMA GEMM -> Q*scale,
// K pre-permuted chunk layout, V^T fp16 pre-swizzled) ; k_attn (flash,
// fixed-offset softmax exp(s-4), l via ones-MFMA, P.V in fp16, 2 q-tiles
// per wave, global_load_lds staging) ; k_proj.
// ws (17 MB high-water, proven safe in R4): Qg@0 Kg@4M Vt@8M mb@12M
// flag@12M+512K Oa@13M.

#define EDIM 128
#define SCALE 0.17677669529663687f

typedef unsigned int uint32;
typedef float f32x4 __attribute__((ext_vector_type(4)));
typedef short s16x8 __attribute__((ext_vector_type(8)));
typedef _Float16 f16x2 __attribute__((ext_vector_type(2)));
typedef _Float16 f16x4 __attribute__((ext_vector_type(4)));
typedef _Float16 f16x8 __attribute__((ext_vector_type(8)));
typedef __fp16 g16x2 __attribute__((ext_vector_type(2)));

__device__ inline float bf2f(ushort u) { return __uint_as_float(((uint32)u) << 16); }
__device__ inline ushort f2bf(float f) {            // round-to-nearest-even
  uint32 u = __float_as_uint(f);
  u += 0x7fffu + ((u >> 16) & 1u);
  return (ushort)(u >> 16);
}
__device__ inline f16x2 pkrtz(float a, float b) {   // v_cvt_pkrtz_f16_f32
  g16x2 t = __builtin_amdgcn_cvt_pkrtz(a, b);
  return __builtin_bit_cast(f16x2, t);
}

__device__ inline f32x4 mfma32(s16x8 a, s16x8 b, f32x4 c) {
  return __builtin_amdgcn_mfma_f32_16x16x32_bf16(a, b, c, 0, 0, 0);
}
__device__ inline f32x4 mfma32h(f16x8 a, f16x8 b, f32x4 c) {
  return __builtin_amdgcn_mfma_f32_16x16x32_f16(a, b, c, 0, 0, 0);
}

#if __has_builtin(__builtin_amdgcn_global_load_lds)
#define HAVE_GLL 1
__device__ inline void gll16(const void* g, void* l) {
  __builtin_amdgcn_global_load_lds(
      (const __attribute__((address_space(1))) unsigned int*)g,
      (__attribute__((address_space(3))) unsigned int*)l, 16, 0, 0);
}
#else
#define HAVE_GLL 0
#endif

// Load 8 consecutive elements as bf16 frag from fp32 or bf16 array.
__device__ inline s16x8 load8(const void* p, size_t e, int fp32) {
  if (fp32) {
    const float* f = (const float*)p + e;
    float4 lo = *(const float4*)f;
    float4 hi = *(const float4*)(f + 4);
    s16x8 r;
    r[0] = (short)f2bf(lo.x); r[1] = (short)f2bf(lo.y);
    r[2] = (short)f2bf(lo.z); r[3] = (short)f2bf(lo.w);
    r[4] = (short)f2bf(hi.x); r[5] = (short)f2bf(hi.y);
    r[6] = (short)f2bf(hi.z); r[7] = (short)f2bf(hi.w);
    return r;
  }
  return *(const s16x8*)((const ushort*)p + e);
}
__device__ inline float loads(const void* p, size_t e, int fp32) {
  return fp32 ? ((const float*)p)[e] : bf2f(((const ushort*)p)[e]);
}

// ---------------- mask: adj[0] -> bitmask (bit=1 keep); block 0 also sniffs
// input dtype (even halfwords of x: bf16 exponents in-range ~100% vs ~16%).
__global__ __launch_bounds__(256) void k_mask(const int* __restrict__ adj,
                                              uint32* __restrict__ mb,
                                              const ushort* __restrict__ xus,
                                              int* __restrict__ flag) {
  if (blockIdx.x == 0 && threadIdx.x < 64) {
    int lane = threadIdx.x, cnt = 0;
#pragma unroll
    for (int i = 0; i < 4; i++) {
      ushort v = xus[2 * (lane * 4 + i)];
      int ex = (v >> 7) & 0xFF;
      cnt += (ex >= 100 && ex <= 140) ? 1 : 0;
    }
#pragma unroll
    for (int s = 1; s < 64; s <<= 1) cnt += __shfl_xor(cnt, s);
    if (lane == 0) *flag = (cnt < 128) ? 1 : 0;   // 1 = fp32
  }
  int idx = blockIdx.x * 256 + threadIdx.x;
  int a = adj[idx];
  unsigned long long bal = __ballot(a != 0);
  int lane = threadIdx.x & 63;
  if (lane == 0)  mb[idx >> 5] = (uint32)bal;
  if (lane == 32) mb[idx >> 5] = (uint32)(bal >> 32);
}

// ---------------- QKV projection: x(16384x128) @ W^T(128x384) + b
// K layout: per (bh, 128-key chunk): 128 "slot" rows x 32 dims, slots in MFMA
// row order (slot s<16 <-> key (s>>2)*8+(s&3); s>=16 <-> +4), so k_attn LDS
// reads are lane-linear. Vt layout: fp16, pre-swizzled granules (g^(d&7)).
__global__ __launch_bounds__(256) void k_qkv(const void* __restrict__ x,
                                             const void* __restrict__ w,
                                             const void* __restrict__ bias,
                                             ushort* __restrict__ Qg,
                                             ushort* __restrict__ Kg,
                                             _Float16* __restrict__ Vth,
                                             const int* __restrict__ flagp) {
  const int fp32 = *flagp;
  const int tid = threadIdx.x;
  const int wave = tid >> 6, lane = tid & 63, L = lane & 15, quad = lane >> 4;
  const int mt = blockIdx.x * 64 + wave * 16;
  const int jt0 = blockIdx.y * 8;

  s16x8 a[4];
#pragma unroll
  for (int ks = 0; ks < 4; ks++)
    a[ks] = load8(x, (size_t)(mt + L) * EDIM + ks * 32 + quad * 8, fp32);

  const int bidx = mt >> 11;                 // batch
  const int npos0 = (mt & 2047) + quad * 4;  // n of reg 0 (mult of 4)

  for (int jj = 0; jj < 8; jj++) {
    int jt = jt0 + jj;
    f32x4 acc = {0.f, 0.f, 0.f, 0.f};
#pragma unroll
    for (int ks = 0; ks < 4; ks++) {
      s16x8 bf = load8(w, (size_t)(jt * 16 + L) * EDIM + ks * 32 + quad * 8, fp32);
      acc = mfma32(a[ks], bf, acc);
    }
    int j = jt * 16 + L;
    float badd = loads(bias, j, fp32);
    int jm = j & 127;
    int h = jm >> 5, d = jm & 31;
    int bh = bidx * 4 + h;
    int ch = npos0 >> 7, kk = npos0 & 127;
    if (jt < 8) {              // Q, pre-scaled
#pragma unroll
      for (int r = 0; r < 4; r++)
        Qg[(size_t)bh * 65536 + (size_t)(npos0 + r) * 32 + d] = f2bf((acc[r] + badd) * SCALE);
    } else if (jt < 16) {      // K, permuted slots
      int sub = kk >> 5, k32 = kk & 31, t = k32 >> 3, r8 = k32 & 7;  // r8%4==0
      int slot0 = sub * 32 + ((r8 >> 2) << 4) + t * 4;
      size_t kb = (size_t)bh * 65536 + (size_t)ch * 4096 + (size_t)slot0 * 32 + d;
#pragma unroll
      for (int r = 0; r < 4; r++) Kg[kb + r * 32] = f2bf(acc[r] + badd);
    } else {                   // V fp16, transposed + pre-swizzled
      int g = kk >> 3, e0 = kk & 7;          // e0 in {0,4}
      f16x2 h0 = pkrtz(acc[0] + badd, acc[1] + badd);
      f16x2 h1 = pkrtz(acc[2] + badd, acc[3] + badd);
      f16x4 pk; pk[0] = h0[0]; pk[1] = h0[1]; pk[2] = h1[0]; pk[3] = h1[1];
      *(f16x4*)(Vth + (size_t)bh * 65536 + (size_t)ch * 4096 + d * 128 +
                (g ^ (d & 7)) * 8 + e0) = pk;
    }
  }
}

// ---------------- flash attention. Block = 2 waves; wave = 2 q-tiles (32 q).
// Fixed-offset softmax p=exp(s-4) (invariant; |s|<~10 so no overflow; masked
// p=0 exactly). l accumulated by all-ones MFMA (every lane gets full sum).
__global__ __launch_bounds__(128) void k_attn(const ushort* __restrict__ Qg,
                                              const ushort* __restrict__ Kg,
                                              const _Float16* __restrict__ Vth,
                                              const uint32* __restrict__ mb,
                                              ushort* Oglob, ushort* Oa,
                                              const int* __restrict__ flagp) {
  __shared__ ushort Klds[128 * 32];    // permuted slot rows
  __shared__ ushort Vlds[32 * 128];    // fp16 bits, swizzled granules

  const int fp32 = *flagp;
  ushort* O = fp32 ? Oa : Oglob;

  const int tid = threadIdx.x;
  const int wv = tid >> 6, lane = tid & 63, L = lane & 15, quad = lane >> 4;
  const int bh = blockIdx.x >> 5;
  const int q0 = (blockIdx.x & 31) * 64 + wv * 32;
  const int qgA = q0 + L, qgB = q0 + 16 + L;

  const ushort* Qb = Qg + (size_t)bh * 65536;
  s16x8 qfA = *(const s16x8*)(Qb + (size_t)qgA * 32 + quad * 8);
  s16x8 qfB = *(const s16x8*)(Qb + (size_t)qgB * 32 + quad * 8);

  f32x4 OA0 = {0,0,0,0}, OA1 = {0,0,0,0}, OB0 = {0,0,0,0}, OB1 = {0,0,0,0};
  f32x4 LA = {0,0,0,0}, LB = {0,0,0,0};
  f16x8 ones;
#pragma unroll
  for (int i = 0; i < 8; i++) ones[i] = (_Float16)1.0f;

  const char* Kg8 = (const char*)(Kg + (size_t)bh * 65536);
  const char* Vg8 = (const char*)(Vth + (size_t)bh * 65536);

  for (int c = 0; c < 16; c++) {
    __syncthreads();
#if HAVE_GLL
#pragma unroll
    for (int j = 0; j < 4; j++) {                  // 2 waves x 4 x 1KB = 8KB each
      int off = (wv + 2 * j) * 1024;
      gll16(Kg8 + (size_t)c * 8192 + off + lane * 16, (char*)Klds + off);
      gll16(Vg8 + (size_t)c * 8192 + off + lane * 16, (char*)Vlds + off);
    }
#else
#pragma unroll
    for (int r = 0; r < 4; r++) {
      int idx = r * 128 + tid;                     // 512 x 16B
      *(s16x8*)((char*)Klds + idx * 16) = *(const s16x8*)(Kg8 + (size_t)c * 8192 + idx * 16);
      *(s16x8*)((char*)Vlds + idx * 16) = *(const s16x8*)(Vg8 + (size_t)c * 8192 + idx * 16);
    }
#endif
    __syncthreads();

    uint4 mA = *(const uint4*)(mb + (size_t)qgA * 64 + c * 4);
    uint4 mB = *(const uint4*)(mb + (size_t)qgB * 64 + c * 4);
    uint32 mAw[4] = {mA.x, mA.y, mA.z, mA.w};
    uint32 mBw[4] = {mB.x, mB.y, mB.z, mB.w};

#pragma unroll
    for (int sub = 0; sub < 4; sub++) {
      const f32x4 Z = {0, 0, 0, 0};
      s16x8 kf0 = *(const s16x8*)&Klds[(sub * 32 + L) * 32 + quad * 8];
      s16x8 kf1 = *(const s16x8*)&Klds[(sub * 32 + 16 + L) * 32 + quad * 8];
      f32x4 sA0 = mfma32(kf0, qfA, Z), sA1 = mfma32(kf1, qfA, Z);
      f32x4 sB0 = mfma32(kf0, qfB, Z), sB1 = mfma32(kf1, qfB, Z);

      uint32 mwqA = mAw[sub] >> (quad * 8);
      uint32 mwqB = mBw[sub] >> (quad * 8);
      union { f16x8 v; f16x2 h[4]; } pA, pB;
      float a0 = ((mwqA >> 0) & 1u) ? __expf(sA0[0] - 4.f) : 0.f;
      float a1 = ((mwqA >> 1) & 1u) ? __expf(sA0[1] - 4.f) : 0.f;
      float a2 = ((mwqA >> 2) & 1u) ? __expf(sA0[2] - 4.f) : 0.f;
      float a3 = ((mwqA >> 3) & 1u) ? __expf(sA0[3] - 4.f) : 0.f;
      float a4 = ((mwqA >> 4) & 1u) ? __expf(sA1[0] - 4.f) : 0.f;
      float a5 = ((mwqA >> 5) & 1u) ? __expf(sA1[1] - 4.f) : 0.f;
      float a6 = ((mwqA >> 6) & 1u) ? __expf(sA1[2] - 4.f) : 0.f;
      float a7 = ((mwqA >> 7) & 1u) ? __expf(sA1[3] - 4.f) : 0.f;
      pA.h[0] = pkrtz(a0, a1);
      pA.h[1] = pkrtz(a2, a3);
      pA.h[2] = pkrtz(a4, a5);
      pA.h[3] = pkrtz(a6, a7);
      float b0 = ((mwqB >> 0) & 1u) ? __expf(sB0[0] - 4.f) : 0.f;
      float b1 = ((mwqB >> 1) & 1u) ? __expf(sB0[1] - 4.f) : 0.f;
      float b2 = ((mwqB >> 2) & 1u) ? __expf(sB0[2] - 4.f) : 0.f;
      float b3 = ((mwqB >> 3) & 1u) ? __expf(sB0[3] - 4.f) : 0.f;
      float b4 = ((mwqB >> 4) & 1u) ? __expf(sB1[0] - 4.f) : 0.f;
      float b5 = ((mwqB >> 5) & 1u) ? __expf(sB1[1] - 4.f) : 0.f;
      float b6 = ((mwqB >> 6) & 1u) ? __expf(sB1[2] - 4.f) : 0.f;
      float b7 = ((mwqB >> 7) & 1u) ? __expf(sB1[3] - 4.f) : 0.f;
      pB.h[0] = pkrtz(b0, b1);
      pB.h[1] = pkrtz(b2, b3);
      pB.h[2] = pkrtz(b4, b5);
      pB.h[3] = pkrtz(b6, b7);

      int g = (sub * 4 + quad) ^ (L & 7);          // same for both d halves
      f16x8 vf0 = *(const f16x8*)&Vlds[L * 128 + g * 8];
      f16x8 vf1 = *(const f16x8*)&Vlds[(16 + L) * 128 + g * 8];
      OA0 = mfma32h(vf0, pA.v, OA0);  OA1 = mfma32h(vf1, pA.v, OA1);
      OB0 = mfma32h(vf0, pB.v, OB0);  OB1 = mfma32h(vf1, pB.v, OB1);
      LA  = mfma32h(ones, pA.v, LA);  LB  = mfma32h(ones, pB.v, LB);
    }
  }

  int b = bh >> 2, h = bh & 3;
  {
    float rn = 1.0f / LA[0];
    size_t ob = ((size_t)(b * 2048 + qgA)) * 128 + h * 32 + quad * 4;
    ushort4 p0, p1;
    p0.x = f2bf(OA0[0] * rn); p0.y = f2bf(OA0[1] * rn);
    p0.z = f2bf(OA0[2] * rn); p0.w = f2bf(OA0[3] * rn);
    p1.x = f2bf(OA1[0] * rn); p1.y = f2bf(OA1[1] * rn);
    p1.z = f2bf(OA1[2] * rn); p1.w = f2bf(OA1[3] * rn);
    *(ushort4*)(O + ob) = p0; *(ushort4*)(O + ob + 16) = p1;
  }
  {
    float rn = 1.0f / LB[0];
    size_t ob = ((size_t)(b * 2048 + qgB)) * 128 + h * 32 + quad * 4;
    ushort4 p0, p1;
    p0.x = f2bf(OB0[0] * rn); p0.y = f2bf(OB0[1] * rn);
    p0.z = f2bf(OB0[2] * rn); p0.w = f2bf(OB0[3] * rn);
    p1.x = f2bf(OB1[0] * rn); p1.y = f2bf(OB1[1] * rn);
    p1.z = f2bf(OB1[2] * rn); p1.w = f2bf(OB1[3] * rn);
    *(ushort4*)(O + ob) = p0; *(ushort4*)(O + ob + 16) = p1;
  }
}

// ---------------- output projection: act @ out_w^T + out_b.
// bf16 mode: in-place on d_out. fp32 mode: Oa(bf16) -> d_out fp32.
__global__ __launch_bounds__(256) void k_proj(void* outp, const ushort* Oa,
                                              const void* w, const void* bias,
                                              const int* flagp) {
  const int fp32 = *flagp;
  const ushort* src = fp32 ? Oa : (const ushort*)outp;
  const int tid = threadIdx.x;
  const int wave = tid >> 6, lane = tid & 63, L = lane & 15, quad = lane >> 4;
  const int mt = blockIdx.x * 64 + wave * 16;

  s16x8 a[4];
#pragma unroll
  for (int ks = 0; ks < 4; ks++)
    a[ks] = *(const s16x8*)(src + (size_t)(mt + L) * EDIM + ks * 32 + quad * 8);

  for (int jt = 0; jt < 8; jt++) {
    f32x4 acc = {0.f, 0.f, 0.f, 0.f};
#pragma unroll
    for (int ks = 0; ks < 4; ks++) {
      s16x8 bf = load8(w, (size_t)(jt * 16 + L) * EDIM + ks * 32 + quad * 8, fp32);
      acc = mfma32(a[ks], bf, acc);
    }
    float badd = loads(bias, jt * 16 + L, fp32);
#pragma unroll
    for (int r = 0; r < 4; r++) {
      size_t idx = (size_t)(mt + quad * 4 + r) * EDIM + jt * 16 + L;
      if (fp32) ((float*)outp)[idx] = acc[r] + badd;
      else      ((ushort*)outp)[idx] = f2bf(acc[r] + badd);
    }
  }
}

extern "C" void kernel_launch(void* const* d_in, const int* in_sizes, int n_in,
                              void* d_out, int out_size, void* d_ws, size_t ws_size,
                              hipStream_t stream) {
  const void* x   = d_in[0];
  const int*  adj = (const int*)d_in[1];
  const void* ipw = d_in[2];
  const void* ipb = d_in[3];
  const void* ow  = d_in[4];
  const void* ob  = d_in[5];

  char* ws = (char*)d_ws;
  ushort*   Qg  = (ushort*)(ws);
  ushort*   Kg  = (ushort*)(ws + ((size_t)4 << 20));
  _Float16* Vth = (_Float16*)(ws + ((size_t)8 << 20));
  uint32*   mb  = (uint32*)(ws + ((size_t)12 << 20));
  int*      fl  = (int*)(ws + ((size_t)12 << 20) + (512 << 10));
  ushort*   Oa  = (ushort*)(ws + ((size_t)13 << 20));   // fp32 mode only

  hipLaunchKernelGGL(k_mask, dim3(16384), dim3(256), 0, stream, adj, mb,
                     (const ushort*)x, fl);
  hipLaunchKernelGGL(k_qkv, dim3(256, 3), dim3(256), 0, stream, x, ipw, ipb,
                     Qg, Kg, Vth, fl);
  hipLaunchKernelGGL(k_attn, dim3(1024), dim3(128), 0, stream, Qg, Kg, Vth, mb,
                     (ushort*)d_out, Oa, fl);
  hipLaunchKernelGGL(k_proj, dim3(256), dim3(256), 0, stream, d_out, Oa, ow, ob, fl);
}